// Round 1
// baseline (220.506 us; speedup 1.0000x reference)
//
#include <hip/hip_runtime.h>

namespace {

constexpr int   kC      = 9;
constexpr int   kH      = 80;
constexpr int   kHid    = 100;
constexpr float kNeg    = 0.1f;
constexpr int   kB      = 16;
constexpr int   kVoxLoc = 2 * kC * kH;   // 1440 voxels per batch group
constexpr int   kCells  = 8192;          // interp cells over ts in [-1, 1]
constexpr int   kTM     = kCells + 1;    // table entries (8193)
constexpr float kInvDelta = 4096.0f;     // cells per unit ts
constexpr float kDelta    = 1.0f / 4096.0f;
constexpr int   kShift    = 512;         // cells per bin shift of 1/8 (exact)
constexpr int   kThreads  = 256;
constexpr int   kBlocksPerGroup = 32;

__device__ __forceinline__ float lrelu(float z) { return z >= 0.f ? z : kNeg * z; }

} // namespace

__global__ void zero_out_kernel(float* __restrict__ out, int n) {
  int i = blockIdx.x * blockDim.x + threadIdx.x;
  if (i < n) out[i] = 0.f;
}

// The lrelu MLP is exactly piecewise-linear in its scalar input, so we
// tabulate it once per launch and linearly interpolate (exact except in
// kink cells, error ~2e-5 there). 4 threads cooperate per table point:
// thread q handles hidden columns k == q (mod 4) so the W2 loads of a wave
// cover one contiguous 16B segment (4 consecutive floats).
__global__ __launch_bounds__(256) void build_table_kernel(
    const float* __restrict__ W1, const float* __restrict__ b1,
    const float* __restrict__ W2, const float* __restrict__ b2,
    const float* __restrict__ W3, const float* __restrict__ b3,
    float* __restrict__ tab) {
  int tid = blockIdx.x * blockDim.x + threadIdx.x;
  int pt = tid >> 2;
  int q  = tid & 3;
  if (pt >= kTM) return;
  float ts = -1.0f + (float)pt * kDelta;

  float h1[kHid];
#pragma unroll
  for (int j = 0; j < kHid; ++j) h1[j] = lrelu(fmaf(ts, W1[j], b1[j]));

  float acc = 0.f;
  for (int kk = 0; kk < kHid / 4; ++kk) {
    int k = 4 * kk + q;
    float a0 = 0.f, a1 = 0.f, a2 = 0.f, a3 = 0.f;
#pragma unroll
    for (int j = 0; j < kHid; j += 4) {
      a0 = fmaf(h1[j + 0], W2[(j + 0) * kHid + k], a0);
      a1 = fmaf(h1[j + 1], W2[(j + 1) * kHid + k], a1);
      a2 = fmaf(h1[j + 2], W2[(j + 2) * kHid + k], a2);
      a3 = fmaf(h1[j + 3], W2[(j + 3) * kHid + k], a3);
    }
    float z = lrelu((a0 + a1) + (a2 + a3) + b2[k]);
    acc = fmaf(z, W3[k], acc);
  }
  // combine the 4 column-subset partials (lanes q=0..3 of each point)
  acc += __shfl_xor(acc, 1);
  acc += __shfl_xor(acc, 2);
  if (q == 0) tab[pt] = acc + b3[0];
}

// Events are sorted by batch group b (b = i*B/N), so each block handles a
// contiguous chunk inside one group and accumulates into a private
// 1440-float LDS voxel slice. Output layout (transpose folded in):
// out[b*1440 + bin*160 + p*80 + (x-1)], scaled by 1/100 at the global add.
__global__ __launch_bounds__(kThreads) void scatter_kernel(
    const float4* __restrict__ events, const float* __restrict__ tab,
    float* __restrict__ out, int Ngroup) {
  __shared__ float s_tab[kTM];      // 32772 B
  __shared__ float s_vox[kVoxLoc];  // 5760 B

  for (int i = threadIdx.x; i < kTM; i += kThreads) s_tab[i] = tab[i];
  for (int i = threadIdx.x; i < kVoxLoc; i += kThreads) s_vox[i] = 0.f;
  __syncthreads();

  int g   = blockIdx.x / kBlocksPerGroup;
  int sub = blockIdx.x % kBlocksPerGroup;
  int per = (Ngroup + kBlocksPerGroup - 1) / kBlocksPerGroup;
  int start = g * Ngroup + sub * per;
  int end   = g * Ngroup + min((sub + 1) * per, Ngroup);

  for (int i = start + (int)threadIdx.x; i < end; i += kThreads) {
    float4 e = events[i];              // (x, t, p, b)
    float t = e.y;
    int base = (int)e.z * kH + (int)e.x - 1;   // p*80 + (x-1), in [0,160)
    // u0 = (t+1)*4096; one floor+frac serves all bins since 1/8 == 512 cells
    float u0 = fmaf(t, kInvDelta, kInvDelta);
    int   k0 = (int)u0;                // u0 >= 4096 > 0, trunc == floor
    float fr = u0 - (float)k0;
#pragma unroll
    for (int bin = 0; bin < kC; ++bin) {
      int k = k0 - kShift * bin;       // in [0, 8191]
      float f0 = s_tab[k];
      float f1 = s_tab[k + 1];
      float f  = fmaf(fr, f1 - f0, f0);
      atomicAdd(&s_vox[bin * (2 * kH) + base], t * f);
    }
  }
  __syncthreads();

  float* og = out + g * kVoxLoc;
  for (int i = threadIdx.x; i < kVoxLoc; i += kThreads) {
    atomicAdd(&og[i], s_vox[i] * 0.01f);
  }
}

extern "C" void kernel_launch(void* const* d_in, const int* in_sizes, int n_in,
                              void* d_out, int out_size, void* d_ws, size_t ws_size,
                              hipStream_t stream) {
  const float4* events = (const float4*)d_in[0];
  const float* W1 = (const float*)d_in[1];
  const float* b1 = (const float*)d_in[2];
  const float* W2 = (const float*)d_in[3];
  const float* b2 = (const float*)d_in[4];
  const float* W3 = (const float*)d_in[5];
  const float* b3 = (const float*)d_in[6];
  float* out = (float*)d_out;
  float* tab = (float*)d_ws;  // kTM floats = 32772 B

  int N = in_sizes[0] / 4;
  int Ngroup = N / kB;

  zero_out_kernel<<<(out_size + 255) / 256, 256, 0, stream>>>(out, out_size);
  build_table_kernel<<<(kTM * 4 + 255) / 256, 256, 0, stream>>>(
      W1, b1, W2, b2, W3, b3, tab);
  scatter_kernel<<<kB * kBlocksPerGroup, kThreads, 0, stream>>>(
      events, tab, out, Ngroup);
}

// Round 2
// 212.122 us; speedup vs baseline: 1.0395x; 1.0395x over previous
//
#include <hip/hip_runtime.h>

namespace {

constexpr int   kC      = 9;
constexpr int   kH      = 80;
constexpr int   kHid    = 100;
constexpr float kNeg    = 0.1f;
constexpr int   kB      = 16;
constexpr int   kVoxLoc = 2 * kC * kH;   // 1440 voxels per batch group
constexpr int   kCells  = 8192;          // interp cells over ts in [-1, 1]
constexpr int   kTM     = kCells + 1;    // table entries (8193)
constexpr float kInvDelta = 4096.0f;     // cells per unit ts
constexpr float kDelta    = 1.0f / 4096.0f;
constexpr int   kShift    = 512;         // cells per bin shift of 1/8 (exact)
constexpr int   kThreads  = 1024;        // 16 waves/block, 2 blocks/CU -> 32 waves/CU
constexpr int   kBlocksPerGroup = 32;

__device__ __forceinline__ float lrelu(float z) { return z >= 0.f ? z : kNeg * z; }

} // namespace

__global__ void zero_out_kernel(float* __restrict__ out, int n) {
  int i = blockIdx.x * blockDim.x + threadIdx.x;
  if (i < n) out[i] = 0.f;
}

// The lrelu MLP is exactly piecewise-linear in its scalar input, so we
// tabulate it and lerp (exact except in kink cells, err ~2e-5).
// 4 threads per point; thread q owns hidden columns k = 4c+q (25 accs in
// VGPRs). h1[j] is RECOMPUTED per j (1 fma + lrelu) instead of stored in a
// 100-element array — the array version spilled to scratch (~110us).
__global__ __launch_bounds__(256) void build_table_kernel(
    const float* __restrict__ W1, const float* __restrict__ b1,
    const float* __restrict__ W2, const float* __restrict__ b2,
    const float* __restrict__ W3, const float* __restrict__ b3,
    float* __restrict__ tab) {
  int tid = blockIdx.x * blockDim.x + threadIdx.x;
  int pt = tid >> 2;
  int q  = tid & 3;
  if (pt >= kTM) return;
  float ts = -1.0f + (float)pt * kDelta;

  float acc[kHid / 4];
#pragma unroll
  for (int c = 0; c < kHid / 4; ++c) acc[c] = 0.f;

  for (int j = 0; j < kHid; ++j) {
    float h1 = lrelu(fmaf(ts, W1[j], b1[j]));   // wave-uniform scalar loads
    const float* w2row = W2 + j * kHid + q;
#pragma unroll
    for (int c = 0; c < kHid / 4; ++c) {
      acc[c] = fmaf(h1, w2row[4 * c], acc[c]);
    }
  }

  float o = 0.f;
#pragma unroll
  for (int c = 0; c < kHid / 4; ++c) {
    int k = 4 * c + q;
    o = fmaf(lrelu(acc[c] + b2[k]), W3[k], o);
  }
  o += __shfl_xor(o, 1);
  o += __shfl_xor(o, 2);
  if (q == 0) tab[pt] = o + b3[0];
}

// Events are sorted by batch group b (b = i*B/N), so each block handles a
// contiguous chunk inside one group and accumulates into a private
// 1440-float LDS voxel slice. Output layout (transpose folded in):
// out[b*1440 + bin*160 + p*80 + (x-1)], scaled by 1/100 at the global add.
// 1024 threads/block: 16 waves * 2 blocks/CU = 32 waves/CU (latency hiding
// was the round-1 wall: 102us at Occupancy 22.6%, VALUBusy 2.7%).
__global__ __launch_bounds__(kThreads) void scatter_kernel(
    const float4* __restrict__ events, const float* __restrict__ tab,
    float* __restrict__ out, int Ngroup) {
  __shared__ float s_tab[kTM];      // 32772 B
  __shared__ float s_vox[kVoxLoc];  // 5760 B

  for (int i = threadIdx.x; i < kTM; i += kThreads) s_tab[i] = tab[i];
  for (int i = threadIdx.x; i < kVoxLoc; i += kThreads) s_vox[i] = 0.f;
  __syncthreads();

  int g   = blockIdx.x / kBlocksPerGroup;
  int sub = blockIdx.x % kBlocksPerGroup;
  int per = (Ngroup + kBlocksPerGroup - 1) / kBlocksPerGroup;
  int start = g * Ngroup + sub * per;
  int end   = g * Ngroup + min((sub + 1) * per, Ngroup);

  for (int i = start + (int)threadIdx.x; i < end; i += kThreads) {
    float4 e = events[i];              // (x, t, p, b)
    float t = e.y;
    int base = (int)e.z * kH + (int)e.x - 1;   // p*80 + (x-1), in [0,160)
    // u0 = (t+1)*4096; one floor+frac serves all bins since 1/8 == 512 cells
    float u0 = fmaf(t, kInvDelta, kInvDelta);
    int   k0 = (int)u0;                // u0 >= 4096 > 0, trunc == floor
    float fr = u0 - (float)k0;
#pragma unroll
    for (int bin = 0; bin < kC; ++bin) {
      int k = k0 - kShift * bin;       // in [0, 8191]
      float f0 = s_tab[k];             // compiler emits ds_read2_b32
      float f1 = s_tab[k + 1];
      float f  = fmaf(fr, f1 - f0, f0);
      atomicAdd(&s_vox[bin * (2 * kH) + base], t * f);
    }
  }
  __syncthreads();

  float* og = out + g * kVoxLoc;
  for (int i = threadIdx.x; i < kVoxLoc; i += kThreads) {
    atomicAdd(&og[i], s_vox[i] * 0.01f);
  }
}

extern "C" void kernel_launch(void* const* d_in, const int* in_sizes, int n_in,
                              void* d_out, int out_size, void* d_ws, size_t ws_size,
                              hipStream_t stream) {
  const float4* events = (const float4*)d_in[0];
  const float* W1 = (const float*)d_in[1];
  const float* b1 = (const float*)d_in[2];
  const float* W2 = (const float*)d_in[3];
  const float* b2 = (const float*)d_in[4];
  const float* W3 = (const float*)d_in[5];
  const float* b3 = (const float*)d_in[6];
  float* out = (float*)d_out;
  float* tab = (float*)d_ws;  // kTM floats = 32772 B

  int N = in_sizes[0] / 4;
  int Ngroup = N / kB;

  zero_out_kernel<<<(out_size + 255) / 256, 256, 0, stream>>>(out, out_size);
  build_table_kernel<<<(kTM * 4 + 255) / 256, 256, 0, stream>>>(
      W1, b1, W2, b2, W3, b3, tab);
  scatter_kernel<<<kB * kBlocksPerGroup, kThreads, 0, stream>>>(
      events, tab, out, Ngroup);
}

// Round 3
// 207.140 us; speedup vs baseline: 1.0645x; 1.0241x over previous
//
#include <hip/hip_runtime.h>

namespace {

constexpr int   kC      = 9;
constexpr int   kH      = 80;
constexpr int   kHid    = 100;
constexpr float kNeg    = 0.1f;
constexpr int   kB      = 16;
constexpr int   kVoxLoc = 2 * kC * kH;   // 1440 voxels per batch group
constexpr int   kCells  = 8192;          // interp cells over ts in [-1, 1]
constexpr int   kTM     = kCells + 1;    // table entries (8193)
constexpr float kInvDelta = 4096.0f;     // cells per unit ts
constexpr float kDelta    = 1.0f / 4096.0f;
constexpr int   kShift    = 512;         // cells per bin shift of 1/8 (exact)
constexpr int   kThreads  = 1024;
constexpr int   kBlocksPerGroup = 32;
// d_ws layout: [0, 32772) scalar tab (8193 f32); [34816, 100352) float2 tab2
constexpr size_t kTab2Off = 34816;

__device__ __forceinline__ float lrelu(float z) { return z >= 0.f ? z : kNeg * z; }

} // namespace

__global__ void zero_out_kernel(float* __restrict__ out, int n) {
  int i = blockIdx.x * blockDim.x + threadIdx.x;
  if (i < n) out[i] = 0.f;
}

// lrelu MLP is exactly piecewise-linear in its scalar input -> tabulate +
// lerp (err ~1e-3 at 8192 cells, threshold 5.5e-3). 4 threads/point, thread q
// owns hidden cols k = 4c+q; h1 recomputed per j (array version spilled).
__global__ __launch_bounds__(256) void build_table_kernel(
    const float* __restrict__ W1, const float* __restrict__ b1,
    const float* __restrict__ W2, const float* __restrict__ b2,
    const float* __restrict__ W3, const float* __restrict__ b3,
    float* __restrict__ tab) {
  int tid = blockIdx.x * blockDim.x + threadIdx.x;
  int pt = tid >> 2;
  int q  = tid & 3;
  if (pt >= kTM) return;
  float ts = -1.0f + (float)pt * kDelta;

  float acc[kHid / 4];
#pragma unroll
  for (int c = 0; c < kHid / 4; ++c) acc[c] = 0.f;

  for (int j = 0; j < kHid; ++j) {
    float h1 = lrelu(fmaf(ts, W1[j], b1[j]));
    const float* w2row = W2 + j * kHid + q;
#pragma unroll
    for (int c = 0; c < kHid / 4; ++c) {
      acc[c] = fmaf(h1, w2row[4 * c], acc[c]);
    }
  }

  float o = 0.f;
#pragma unroll
  for (int c = 0; c < kHid / 4; ++c) {
    int k = 4 * c + q;
    o = fmaf(lrelu(acc[c] + b2[k]), W3[k], o);
  }
  o += __shfl_xor(o, 1);
  o += __shfl_xor(o, 2);
  if (q == 0) tab[pt] = o + b3[0];
}

// Pack (value, delta) pairs so the scatter kernel's lerp needs ONE 8B global
// gather per bin instead of two LDS reads (round-2 showed the LDS pipe is the
// per-CU bottleneck: time invariant to occupancy 23%->77%, VALUBusy 3%).
__global__ void pack_table_kernel(const float* __restrict__ tab,
                                  float2* __restrict__ tab2) {
  int k = blockIdx.x * blockDim.x + threadIdx.x;
  if (k < kCells) {
    float a = tab[k], b = tab[k + 1];
    tab2[k] = make_float2(a, b - a);
  }
}

// Events are sorted by batch group b (b = i*B/N): each block handles a
// contiguous chunk of one group, accumulating into a private 1440-float LDS
// slice. Table reads go through the VECTOR-MEMORY pipe (L1/L2-cached 64KB
// float2 table) so the LDS pipe only carries the 9 ds_add_f32 per event.
// Output layout (transpose folded): out[b*1440 + bin*160 + p*80 + (x-1)],
// scaled by 1/100 at the global-atomic tail.
__global__ __launch_bounds__(kThreads) void scatter_kernel(
    const float4* __restrict__ events, const float2* __restrict__ tab2,
    float* __restrict__ out, int Ngroup) {
  __shared__ float s_vox[kVoxLoc];  // 5760 B
  for (int i = threadIdx.x; i < kVoxLoc; i += kThreads) s_vox[i] = 0.f;
  __syncthreads();

  int g   = blockIdx.x / kBlocksPerGroup;
  int sub = blockIdx.x % kBlocksPerGroup;
  int per = (Ngroup + kBlocksPerGroup - 1) / kBlocksPerGroup;
  int start = g * Ngroup + sub * per;
  int end   = g * Ngroup + min((sub + 1) * per, Ngroup);

  for (int i = start + (int)threadIdx.x; i < end; i += kThreads) {
    float4 e = events[i];              // (x, t, p, b)
    float t = e.y;
    int base = (int)e.z * kH + (int)e.x - 1;   // p*80 + (x-1), in [0,160)
    float u0 = fmaf(t, kInvDelta, kInvDelta);  // (t+1)*4096
    int   k0 = (int)u0;                        // in [4096, 8192)
    float fr = u0 - (float)k0;

    // issue all 9 independent gathers first (MLP for latency hiding)
    float2 v[kC];
#pragma unroll
    for (int bin = 0; bin < kC; ++bin) v[bin] = tab2[k0 - kShift * bin];
#pragma unroll
    for (int bin = 0; bin < kC; ++bin) {
      float f = fmaf(fr, v[bin].y, v[bin].x);
      atomicAdd(&s_vox[bin * (2 * kH) + base], t * f);
    }
  }
  __syncthreads();

  float* og = out + g * kVoxLoc;
  for (int i = threadIdx.x; i < kVoxLoc; i += kThreads) {
    atomicAdd(&og[i], s_vox[i] * 0.01f);
  }
}

extern "C" void kernel_launch(void* const* d_in, const int* in_sizes, int n_in,
                              void* d_out, int out_size, void* d_ws, size_t ws_size,
                              hipStream_t stream) {
  const float4* events = (const float4*)d_in[0];
  const float* W1 = (const float*)d_in[1];
  const float* b1 = (const float*)d_in[2];
  const float* W2 = (const float*)d_in[3];
  const float* b2 = (const float*)d_in[4];
  const float* W3 = (const float*)d_in[5];
  const float* b3 = (const float*)d_in[6];
  float* out = (float*)d_out;
  float*  tab  = (float*)d_ws;
  float2* tab2 = (float2*)((char*)d_ws + kTab2Off);

  int N = in_sizes[0] / 4;
  int Ngroup = N / kB;

  zero_out_kernel<<<(out_size + 255) / 256, 256, 0, stream>>>(out, out_size);
  build_table_kernel<<<(kTM * 4 + 255) / 256, 256, 0, stream>>>(
      W1, b1, W2, b2, W3, b3, tab);
  pack_table_kernel<<<(kCells + 255) / 256, 256, 0, stream>>>(tab, tab2);
  scatter_kernel<<<kB * kBlocksPerGroup, kThreads, 0, stream>>>(
      events, tab2, out, Ngroup);
}

// Round 4
// 192.147 us; speedup vs baseline: 1.1476x; 1.0780x over previous
//
#include <hip/hip_runtime.h>
#include <hip/hip_fp16.h>

namespace {

constexpr int   kC      = 9;
constexpr int   kH      = 80;
constexpr int   kHid    = 100;
constexpr float kNeg    = 0.1f;
constexpr int   kB      = 16;
constexpr int   kVoxLoc = 2 * kC * kH;   // 1440 voxels per batch group
constexpr int   kCells  = 8192;          // interp cells over ts in [-1, 1]
constexpr int   kTM     = kCells + 1;    // table entries (8193)
constexpr float kInvDelta = 4096.0f;
constexpr float kDelta    = 1.0f / 4096.0f;
constexpr int   kShift    = 512;         // cells per bin shift of 1/8 (exact)
constexpr int   kThreads  = 1024;
constexpr int   kBlocksPerGroup = 32;
constexpr int   kK0Base   = 4096;        // k0 = (t+1)*4096 in [4096, 8192)
// d_ws: [0, 32772) scalar tab; [65536, 65536+262144) packed Entry9 table
constexpr size_t kTab9Off = 65536;

__device__ __forceinline__ float lrelu(float z) { return z >= 0.f ? z : kNeg * z; }

// One 64B cache line per event: 9 fp32 values + 9 fp16 lerp-deltas.
struct alignas(16) Entry9 {
  float  v[9];     // 36 B
  __half d[9];     // 18 B
  __half pad[5];   // -> 64 B
};
static_assert(sizeof(Entry9) == 64, "Entry9 must be 64B");

union EntryLd { float4 q[4]; Entry9 e; };

} // namespace

__global__ void zero_out_kernel(float* __restrict__ out, int n) {
  int i = blockIdx.x * blockDim.x + threadIdx.x;
  if (i < n) out[i] = 0.f;
}

// Wave-per-point table build: round-3's 128-block version was load-latency
// bound at 2 waves/CU (~90us hidden in the total). Here: 8193 waves (32/CU),
// lane owns hidden column `lane` (and 64+lane for lanes<36); W2 row loads
// are coalesced 256B/144B per instruction; shuffle-reduce at the end.
__global__ __launch_bounds__(256) void build_table_kernel(
    const float* __restrict__ W1, const float* __restrict__ b1,
    const float* __restrict__ W2, const float* __restrict__ b2,
    const float* __restrict__ W3, const float* __restrict__ b3,
    float* __restrict__ tab) {
  int wave = (blockIdx.x * 256 + threadIdx.x) >> 6;
  int lane = threadIdx.x & 63;
  if (wave >= kTM) return;
  float ts = -1.0f + (float)wave * kDelta;

  bool two = (lane < kHid - 64);   // lanes 0..35 own a second column
  float acc1 = 0.f, acc2 = 0.f;
  for (int j = 0; j < kHid; ++j) {
    float h1 = lrelu(fmaf(ts, W1[j], b1[j]));   // W1[j]/b1[j] wave-uniform
    const float* row = W2 + j * kHid;
    acc1 = fmaf(h1, row[lane], acc1);
    float w2b = two ? row[64 + lane] : 0.f;
    acc2 = fmaf(h1, w2b, acc2);
  }
  float o = lrelu(acc1 + b2[lane]) * W3[lane];
  if (two) o += lrelu(acc2 + b2[64 + lane]) * W3[64 + lane];
#pragma unroll
  for (int off = 32; off >= 1; off >>= 1) o += __shfl_xor(o, off);
  if (lane == 0) tab[wave] = o + b3[0];
}

// Pack all 9 bins' (value, fp16 delta) for each k0 into ONE 64B record so the
// scatter kernel touches exactly one cache line per event (round-3 evidence:
// 9 scattered 8B gathers/event left scatter stuck at 95us regardless of
// whether they went through LDS or L1 — line/miss throughput is the wall).
__global__ void pack_table9_kernel(const float* __restrict__ tab,
                                   Entry9* __restrict__ tab9) {
  int i = blockIdx.x * blockDim.x + threadIdx.x;
  if (i >= kCells - kK0Base + 1 + 4095) return;  // 4096 entries
  if (i >= 4096) return;
  EntryLd u;
#pragma unroll
  for (int b = 0; b < kC; ++b) {
    int k = i + kK0Base - kShift * b;       // in [0, 8191]
    float a = tab[k];
    u.e.v[b] = a;
    u.e.d[b] = __float2half(tab[k + 1] - a);
  }
#pragma unroll
  for (int b = 0; b < 5; ++b) u.e.pad[b] = __half(0.f);
  float4* dst = reinterpret_cast<float4*>(tab9 + i);
#pragma unroll
  for (int b = 0; b < 4; ++b) dst[b] = u.q[b];
}

// Events are sorted by batch group b (b = i*B/N): each block takes a
// contiguous chunk of one group, accumulating into a private 1440-float LDS
// slice. Per event: one 64B-line read (4x dwordx4) + 9 ds_add_f32.
// Output layout (transpose folded): out[b*1440 + bin*160 + p*80 + (x-1)],
// scaled by 1/100 at the global-atomic tail.
__global__ __launch_bounds__(kThreads) void scatter_kernel(
    const float4* __restrict__ events, const Entry9* __restrict__ tab9,
    float* __restrict__ out, int Ngroup) {
  __shared__ float s_vox[kVoxLoc];  // 5760 B
  for (int i = threadIdx.x; i < kVoxLoc; i += kThreads) s_vox[i] = 0.f;
  __syncthreads();

  int g   = blockIdx.x / kBlocksPerGroup;
  int sub = blockIdx.x % kBlocksPerGroup;
  int per = (Ngroup + kBlocksPerGroup - 1) / kBlocksPerGroup;
  int start = g * Ngroup + sub * per;
  int end   = g * Ngroup + min((sub + 1) * per, Ngroup);

  for (int i = start + (int)threadIdx.x; i < end; i += kThreads) {
    float4 e = events[i];              // (x, t, p, b)
    float t = e.y;
    int base = (int)e.z * kH + (int)e.x - 1;   // p*80 + (x-1), in [0,160)
    float u0 = fmaf(t, kInvDelta, kInvDelta);  // (t+1)*4096
    int   k0 = (int)u0;                        // in [4096, 8192)
    float fr = u0 - (float)k0;

    const float4* ep = reinterpret_cast<const float4*>(tab9 + (k0 - kK0Base));
    EntryLd u;
    u.q[0] = ep[0]; u.q[1] = ep[1]; u.q[2] = ep[2]; u.q[3] = ep[3];
#pragma unroll
    for (int bin = 0; bin < kC; ++bin) {
      float f = fmaf(fr, __half2float(u.e.d[bin]), u.e.v[bin]);
      atomicAdd(&s_vox[bin * (2 * kH) + base], t * f);
    }
  }
  __syncthreads();

  float* og = out + g * kVoxLoc;
  for (int i = threadIdx.x; i < kVoxLoc; i += kThreads) {
    atomicAdd(&og[i], s_vox[i] * 0.01f);
  }
}

extern "C" void kernel_launch(void* const* d_in, const int* in_sizes, int n_in,
                              void* d_out, int out_size, void* d_ws, size_t ws_size,
                              hipStream_t stream) {
  const float4* events = (const float4*)d_in[0];
  const float* W1 = (const float*)d_in[1];
  const float* b1 = (const float*)d_in[2];
  const float* W2 = (const float*)d_in[3];
  const float* b2 = (const float*)d_in[4];
  const float* W3 = (const float*)d_in[5];
  const float* b3 = (const float*)d_in[6];
  float* out = (float*)d_out;
  float*  tab  = (float*)d_ws;
  Entry9* tab9 = (Entry9*)((char*)d_ws + kTab9Off);

  int N = in_sizes[0] / 4;
  int Ngroup = N / kB;

  zero_out_kernel<<<(out_size + 255) / 256, 256, 0, stream>>>(out, out_size);
  // 8193 waves, 4 per 256-thread block
  build_table_kernel<<<(kTM + 3) / 4, 256, 0, stream>>>(
      W1, b1, W2, b2, W3, b3, tab);
  pack_table9_kernel<<<(4096 + 255) / 256, 256, 0, stream>>>(tab, tab9);
  scatter_kernel<<<kB * kBlocksPerGroup, kThreads, 0, stream>>>(
      events, tab9, out, Ngroup);
}

// Round 6
// 152.077 us; speedup vs baseline: 1.4500x; 1.2635x over previous
//
#include <hip/hip_runtime.h>
#include <hip/hip_fp16.h>

namespace {

constexpr int   kC      = 9;
constexpr int   kH      = 80;
constexpr int   kHid    = 100;
constexpr float kNeg    = 0.1f;
constexpr int   kB      = 16;
constexpr int   kBase   = 2 * kH;        // 160 (p,x) slots per group
constexpr int   kVoxLoc = kC * kBase;    // 1440 voxels per batch group
constexpr int   kPairs  = 5;             // 9 bins in 5 packed-f16 slots
constexpr int   kShards = 2;             // wave-parity shards (f16 precision)
constexpr int   kCells  = 8192;          // interp cells over ts in [-1, 1]
constexpr int   kTM     = kCells + 1;    // table entries (8193)
constexpr float kInvDelta = 4096.0f;
constexpr float kDelta    = 1.0f / 4096.0f;
constexpr int   kShift    = 512;         // cells per bin shift of 1/8 (exact)
constexpr int   kThreads  = 1024;
constexpr int   kBlocksPerGroup = 32;
constexpr int   kK0Base   = 4096;        // k0 = (t+1)*4096 in [4096, 8192)
// d_ws: [0, 32772) scalar tab; [65536, +262144) packed Entry9 table
constexpr size_t kTab9Off = 65536;

__device__ __forceinline__ float lrelu(float z) { return z >= 0.f ? z : kNeg * z; }

// One 64B cache line per event: 9 fp32 values + 9 fp16 lerp-deltas.
struct alignas(16) Entry9 {
  float  v[9];     // 36 B
  __half d[9];     // 18 B
  __half pad[5];   // -> 64 B
};
static_assert(sizeof(Entry9) == 64, "Entry9 must be 64B");

union EntryLd { float4 q[4]; Entry9 e; };

typedef _Float16 h2_t __attribute__((ext_vector_type(2)));

// RNE f16 pair pack (v_cvt_f16_f32 + pack); RTZ pkrtz would double the noise.
__device__ __forceinline__ uint32_t pack_f16x2(float lo, float hi) {
  uint32_t l = (uint32_t)__half_as_ushort(__float2half_rn(lo));
  uint32_t h = (uint32_t)__half_as_ushort(__float2half_rn(hi));
  return l | (h << 16);
}

} // namespace

__global__ void zero_out_kernel(float* __restrict__ out, int n) {
  int i = blockIdx.x * blockDim.x + threadIdx.x;
  if (i < n) out[i] = 0.f;
}

// Wave-per-point table build (lrelu MLP is piecewise-linear in its scalar
// input -> tabulate + lerp). Lane owns hidden column `lane` (+64+lane for
// lanes<36); W2 row loads coalesced; shuffle-reduce at the end.
__global__ __launch_bounds__(256) void build_table_kernel(
    const float* __restrict__ W1, const float* __restrict__ b1,
    const float* __restrict__ W2, const float* __restrict__ b2,
    const float* __restrict__ W3, const float* __restrict__ b3,
    float* __restrict__ tab) {
  int wave = (blockIdx.x * 256 + threadIdx.x) >> 6;
  int lane = threadIdx.x & 63;
  if (wave >= kTM) return;
  float ts = -1.0f + (float)wave * kDelta;

  bool two = (lane < kHid - 64);
  float acc1 = 0.f, acc2 = 0.f;
  for (int j = 0; j < kHid; ++j) {
    float h1 = lrelu(fmaf(ts, W1[j], b1[j]));
    const float* row = W2 + j * kHid;
    acc1 = fmaf(h1, row[lane], acc1);
    float w2b = two ? row[64 + lane] : 0.f;
    acc2 = fmaf(h1, w2b, acc2);
  }
  float o = lrelu(acc1 + b2[lane]) * W3[lane];
  if (two) o += lrelu(acc2 + b2[64 + lane]) * W3[64 + lane];
#pragma unroll
  for (int off = 32; off >= 1; off >>= 1) o += __shfl_xor(o, off);
  if (lane == 0) tab[wave] = o + b3[0];
}

// Pack all 9 bins' (value, fp16 delta) per k0 into ONE 64B record (round 4:
// one line per event; gathers proven cheap).
__global__ void pack_table9_kernel(const float* __restrict__ tab,
                                   Entry9* __restrict__ tab9) {
  int i = blockIdx.x * blockDim.x + threadIdx.x;
  if (i >= 4096) return;
  EntryLd u;
#pragma unroll
  for (int b = 0; b < kC; ++b) {
    int k = i + kK0Base - kShift * b;       // in [0, 8191]
    float a = tab[k];
    u.e.v[b] = a;
    u.e.d[b] = __float2half(tab[k + 1] - a);
  }
#pragma unroll
  for (int b = 0; b < 5; ++b) u.e.pad[b] = __float2half(0.f);
  float4* dst = reinterpret_cast<float4*>(tab9 + i);
#pragma unroll
  for (int b = 0; b < 4; ++b) dst[b] = u.q[b];
}

// Measured model (rounds 1-4): LDS atomics cost ~3.2 cyc per LANE per CU,
// invariant to banks/occupancy/gather pipe -> atomic COUNT is the knob.
// This round: 9 ds_add_f32 -> 5 ds_pk_add_f16 (inline asm; no HIP overload
// in ROCm 7.2). Layout s_vox[shard][base][pair]: one address VGPR + offset
// immediates. Two wave-parity shards keep per-slot f16 sums small (~12
// events) so rounding noise stays ~1-2e-3 on the /100 output scale.
__global__ __launch_bounds__(kThreads) void scatter_kernel(
    const float4* __restrict__ events, const Entry9* __restrict__ tab9,
    float* __restrict__ out, int Ngroup) {
  __shared__ uint32_t s_vox[kShards][kBase][kPairs];  // 6400 B
  for (int i = threadIdx.x; i < kShards * kBase * kPairs; i += kThreads)
    (&s_vox[0][0][0])[i] = 0u;
  __syncthreads();

  int g   = blockIdx.x / kBlocksPerGroup;
  int sub = blockIdx.x % kBlocksPerGroup;
  int per = (Ngroup + kBlocksPerGroup - 1) / kBlocksPerGroup;
  int start = g * Ngroup + sub * per;
  int end   = g * Ngroup + min((sub + 1) * per, Ngroup);
  int shard = (threadIdx.x >> 6) & (kShards - 1);   // wave parity

  for (int i = start + (int)threadIdx.x; i < end; i += kThreads) {
    float4 e = events[i];              // (x, t, p, b)
    float t = e.y;
    int base = (int)e.z * kH + (int)e.x - 1;   // p*80 + (x-1), in [0,160)
    float u0 = fmaf(t, kInvDelta, kInvDelta);  // (t+1)*4096
    int   k0 = (int)u0;                        // in [4096, 8192)
    float fr = u0 - (float)k0;

    const float4* ep = reinterpret_cast<const float4*>(tab9 + (k0 - kK0Base));
    EntryLd u;
    u.q[0] = ep[0]; u.q[1] = ep[1]; u.q[2] = ep[2]; u.q[3] = ep[3];

    float f[kC];
#pragma unroll
    for (int bin = 0; bin < kC; ++bin)
      f[bin] = t * fmaf(fr, __half2float(u.e.d[bin]), u.e.v[bin]);

    uint32_t p0 = pack_f16x2(f[0], f[1]);
    uint32_t p1 = pack_f16x2(f[2], f[3]);
    uint32_t p2 = pack_f16x2(f[4], f[5]);
    uint32_t p3 = pack_f16x2(f[6], f[7]);
    uint32_t p4 = pack_f16x2(f[8], 0.f);
    // DS byte address = low 32 bits of the generic LDS pointer (4GB-aligned
    // shared aperture on gfx9+).
    uint32_t a = (uint32_t)(uintptr_t)&s_vox[shard][base][0];
    asm volatile("ds_pk_add_f16 %0, %1"           :: "v"(a), "v"(p0) : "memory");
    asm volatile("ds_pk_add_f16 %0, %1 offset:4"  :: "v"(a), "v"(p1) : "memory");
    asm volatile("ds_pk_add_f16 %0, %1 offset:8"  :: "v"(a), "v"(p2) : "memory");
    asm volatile("ds_pk_add_f16 %0, %1 offset:12" :: "v"(a), "v"(p3) : "memory");
    asm volatile("ds_pk_add_f16 %0, %1 offset:16" :: "v"(a), "v"(p4) : "memory");
  }
  __syncthreads();

  float* og = out + g * kVoxLoc;
  for (int i = threadIdx.x; i < kVoxLoc; i += kThreads) {
    int bin  = i / kBase;              // out layout: [bin][base]
    int base = i - bin * kBase;
    int pr = bin >> 1, hi = bin & 1;
    float v = 0.f;
#pragma unroll
    for (int s = 0; s < kShards; ++s) {
      h2_t hv = __builtin_bit_cast(h2_t, s_vox[s][base][pr]);
      v += (float)hv[hi];
    }
    atomicAdd(&og[i], v * 0.01f);
  }
}

extern "C" void kernel_launch(void* const* d_in, const int* in_sizes, int n_in,
                              void* d_out, int out_size, void* d_ws, size_t ws_size,
                              hipStream_t stream) {
  const float4* events = (const float4*)d_in[0];
  const float* W1 = (const float*)d_in[1];
  const float* b1 = (const float*)d_in[2];
  const float* W2 = (const float*)d_in[3];
  const float* b2 = (const float*)d_in[4];
  const float* W3 = (const float*)d_in[5];
  const float* b3 = (const float*)d_in[6];
  float* out = (float*)d_out;
  float*  tab  = (float*)d_ws;
  Entry9* tab9 = (Entry9*)((char*)d_ws + kTab9Off);

  int N = in_sizes[0] / 4;
  int Ngroup = N / kB;

  zero_out_kernel<<<(out_size + 255) / 256, 256, 0, stream>>>(out, out_size);
  build_table_kernel<<<(kTM + 3) / 4, 256, 0, stream>>>(
      W1, b1, W2, b2, W3, b3, tab);
  pack_table9_kernel<<<(4096 + 255) / 256, 256, 0, stream>>>(tab, tab9);
  scatter_kernel<<<kB * kBlocksPerGroup, kThreads, 0, stream>>>(
      events, tab9, out, Ngroup);
}

// Round 8
// 120.118 us; speedup vs baseline: 1.8357x; 1.2661x over previous
//
#include <hip/hip_runtime.h>
#include <hip/hip_fp16.h>

namespace {

constexpr int   kC      = 9;
constexpr int   kH      = 80;
constexpr int   kHid    = 100;
constexpr float kNeg    = 0.1f;
constexpr int   kB      = 16;
constexpr int   kBase   = 2 * kH;        // 160 (p,x) slots per group
constexpr int   kVoxLoc = kC * kBase;    // 1440 voxels per batch group
constexpr int   kWords  = 3;             // 9 bins in 3 u64 atomics (3 fields each)
constexpr int   kShards = 2;             // wave-parity shards (overflow headroom)
constexpr int   kCells  = 8192;          // interp cells over ts in [-1, 1]
constexpr int   kTM     = kCells + 1;    // table entries (8193)
constexpr float kInvDelta = 4096.0f;
constexpr float kDelta    = 1.0f / 4096.0f;
constexpr int   kShift    = 512;         // cells per bin shift of 1/8 (exact)
constexpr int   kThreads  = 1024;
constexpr int   kBlocksPerGroup = 32;
constexpr int   kK0Base   = 4096;        // k0 = (t+1)*4096 in [4096, 8192)
// Fixed-point packing, round-8 numerics (round 7 failed at 1.245e-2 because
// DETERMINISTIC rint bias accumulates linearly over ~780 events/voxel:
// 781*(1/256)*0.41/100 = 1.25e-2 — exactly measured):
//  * 19-bit fields (count shrunk to 7 bits; <=127 events/slot/shard vs
//    Poisson mean 12) -> scale 512 (4x finer).
//  * UNBIASED DITHER: q = floor(f*512 + u), u = hash(event) in [0,1) ->
//    E[q]/512 = f exactly; residual noise sqrt(781)*0.41/512/100 ~ 2e-4 std.
// u64 = [count:7 (bit 57) | f2:19 | f1:19 | f0:19]; addend = q + 2048,
// |f| clamped to 3.9 -> addend in [0, 4045]; 128 max-addends == 2^19 exact.
constexpr float kScale    = 512.0f;
constexpr float kInvScale = 1.0f / 512.0f;
constexpr int   kBias     = 2048;
// d_ws: [0, 32772) scalar tab; [65536, +262144) packed Entry9 table
constexpr size_t kTab9Off = 65536;

__device__ __forceinline__ float lrelu(float z) { return z >= 0.f ? z : kNeg * z; }

// One 64B cache line per event: 9 fp32 values + 9 fp16 lerp-deltas.
struct alignas(16) Entry9 {
  float  v[9];     // 36 B
  __half d[9];     // 18 B
  __half pad[5];   // -> 64 B
};
static_assert(sizeof(Entry9) == 64, "Entry9 must be 64B");

union EntryLd { float4 q[4]; Entry9 e; };

} // namespace

__global__ void zero_out_kernel(float* __restrict__ out, int n) {
  int i = blockIdx.x * blockDim.x + threadIdx.x;
  if (i < n) out[i] = 0.f;
}

// Wave-per-point table build (lrelu MLP is piecewise-linear in its scalar
// input -> tabulate + lerp). Lane owns hidden column `lane` (+64+lane for
// lanes<36); W2 row loads coalesced; shuffle-reduce at the end.
__global__ __launch_bounds__(256) void build_table_kernel(
    const float* __restrict__ W1, const float* __restrict__ b1,
    const float* __restrict__ W2, const float* __restrict__ b2,
    const float* __restrict__ W3, const float* __restrict__ b3,
    float* __restrict__ tab) {
  int wave = (blockIdx.x * 256 + threadIdx.x) >> 6;
  int lane = threadIdx.x & 63;
  if (wave >= kTM) return;
  float ts = -1.0f + (float)wave * kDelta;

  bool two = (lane < kHid - 64);
  float acc1 = 0.f, acc2 = 0.f;
  for (int j = 0; j < kHid; ++j) {
    float h1 = lrelu(fmaf(ts, W1[j], b1[j]));
    const float* row = W2 + j * kHid;
    acc1 = fmaf(h1, row[lane], acc1);
    float w2b = two ? row[64 + lane] : 0.f;
    acc2 = fmaf(h1, w2b, acc2);
  }
  float o = lrelu(acc1 + b2[lane]) * W3[lane];
  if (two) o += lrelu(acc2 + b2[64 + lane]) * W3[64 + lane];
#pragma unroll
  for (int off = 32; off >= 1; off >>= 1) o += __shfl_xor(o, off);
  if (lane == 0) tab[wave] = o + b3[0];
}

// Pack all 9 bins' (value, fp16 delta) per k0 into ONE 64B record (round 4:
// one line per event; gathers proven cheap).
__global__ void pack_table9_kernel(const float* __restrict__ tab,
                                   Entry9* __restrict__ tab9) {
  int i = blockIdx.x * blockDim.x + threadIdx.x;
  if (i >= 4096) return;
  EntryLd u;
#pragma unroll
  for (int b = 0; b < kC; ++b) {
    int k = i + kK0Base - kShift * b;       // in [0, 8191]
    float a = tab[k];
    u.e.v[b] = a;
    u.e.d[b] = __float2half(tab[k + 1] - a);
  }
#pragma unroll
  for (int b = 0; b < 5; ++b) u.e.pad[b] = __float2half(0.f);
  float4* dst = reinterpret_cast<float4*>(tab9 + i);
#pragma unroll
  for (int b = 0; b < 4; ++b) dst[b] = u.q[b];
}

// Measured model (rounds 1-6): LDS atomics cost ~3.3 cyc/lane/instruction,
// invariant to width (pk_f16 == f32 == u64 expected), banks, occupancy,
// gather pipe -> instruction COUNT is the only knob (round 6: 9->5 ops gave
// exactly 5/9 time). 3 ds_add_u64 per event, dithered fixed-point fields.
__global__ __launch_bounds__(kThreads) void scatter_kernel(
    const float4* __restrict__ events, const Entry9* __restrict__ tab9,
    float* __restrict__ out, int Ngroup) {
  __shared__ unsigned long long s_vox[kShards][kBase][kWords];  // 7680 B
  for (int i = threadIdx.x; i < kShards * kBase * kWords; i += kThreads)
    (&s_vox[0][0][0])[i] = 0ull;
  __syncthreads();

  int g   = blockIdx.x / kBlocksPerGroup;
  int sub = blockIdx.x % kBlocksPerGroup;
  int per = (Ngroup + kBlocksPerGroup - 1) / kBlocksPerGroup;
  int start = g * Ngroup + sub * per;
  int end   = g * Ngroup + min((sub + 1) * per, Ngroup);
  int shard = (threadIdx.x >> 6) & (kShards - 1);   // wave parity

  for (int i = start + (int)threadIdx.x; i < end; i += kThreads) {
    float4 e = events[i];              // (x, t, p, b)
    float t = e.y;
    int base = (int)e.z * kH + (int)e.x - 1;   // p*80 + (x-1), in [0,160)
    float u0 = fmaf(t, kInvDelta, kInvDelta);  // (t+1)*4096
    int   k0 = (int)u0;                        // in [4096, 8192)
    float fr = u0 - (float)k0;

    const float4* ep = reinterpret_cast<const float4*>(tab9 + (k0 - kK0Base));
    EntryLd u;
    u.q[0] = ep[0]; u.q[1] = ep[1]; u.q[2] = ep[2]; u.q[3] = ep[3];

    // per-event dither in [0,1): Knuth multiplicative hash of event index
    float dith = (float)((unsigned)i * 2654435761u >> 8) * (1.0f / 16777216.0f);

    int q[kC];
#pragma unroll
    for (int bin = 0; bin < kC; ++bin) {
      float f = t * fmaf(fr, __half2float(u.e.d[bin]), u.e.v[bin]);
      f = fminf(fmaxf(f, -3.9f), 3.9f);        // guards field overflow
      q[bin] = (int)floorf(fmaf(f, kScale, dith)) + kBias;  // in [0, 4045]
    }
    unsigned long long* sv = &s_vox[shard][base][0];
#pragma unroll
    for (int w = 0; w < kWords; ++w) {
      unsigned long long word =
          (1ull << 57) |
          ((unsigned long long)q[3 * w + 2] << 38) |
          ((unsigned long long)q[3 * w + 1] << 19) |
          (unsigned long long)q[3 * w + 0];
      atomicAdd(&sv[w], word);                 // ds_add_u64
    }
  }
  __syncthreads();

  float* og = out + g * kVoxLoc;
  for (int i = threadIdx.x; i < kVoxLoc; i += kThreads) {
    int bin  = i / kBase;              // out layout: [bin][base]
    int base = i - bin * kBase;
    int w = bin / 3, fld = bin - 3 * w;
    float v = 0.f;
#pragma unroll
    for (int s = 0; s < kShards; ++s) {
      unsigned long long word = s_vox[s][base][w];
      long long cnt = (long long)(word >> 57);
      long long raw = (long long)((word >> (19 * fld)) & 0x7FFFFull);
      v += (float)(raw - cnt * (long long)kBias) * kInvScale;
    }
    atomicAdd(&og[i], v * 0.01f);
  }
}

extern "C" void kernel_launch(void* const* d_in, const int* in_sizes, int n_in,
                              void* d_out, int out_size, void* d_ws, size_t ws_size,
                              hipStream_t stream) {
  const float4* events = (const float4*)d_in[0];
  const float* W1 = (const float*)d_in[1];
  const float* b1 = (const float*)d_in[2];
  const float* W2 = (const float*)d_in[3];
  const float* b2 = (const float*)d_in[4];
  const float* W3 = (const float*)d_in[5];
  const float* b3 = (const float*)d_in[6];
  float* out = (float*)d_out;
  float*  tab  = (float*)d_ws;
  Entry9* tab9 = (Entry9*)((char*)d_ws + kTab9Off);

  int N = in_sizes[0] / 4;
  int Ngroup = N / kB;

  zero_out_kernel<<<(out_size + 255) / 256, 256, 0, stream>>>(out, out_size);
  build_table_kernel<<<(kTM + 3) / 4, 256, 0, stream>>>(
      W1, b1, W2, b2, W3, b3, tab);
  pack_table9_kernel<<<(4096 + 255) / 256, 256, 0, stream>>>(tab, tab9);
  scatter_kernel<<<kB * kBlocksPerGroup, kThreads, 0, stream>>>(
      events, tab9, out, Ngroup);
}

// Round 9
// 118.922 us; speedup vs baseline: 1.8542x; 1.0101x over previous
//
#include <hip/hip_runtime.h>
#include <hip/hip_fp16.h>

namespace {

constexpr int   kC      = 9;
constexpr int   kH      = 80;
constexpr int   kHid    = 100;
constexpr float kNeg    = 0.1f;
constexpr int   kB      = 16;
constexpr int   kBase   = 2 * kH;        // 160 (p,x) slots per group
constexpr int   kVoxLoc = kC * kBase;    // 1440 voxels per batch group
constexpr int   kWords  = 3;             // 9 bins in 3 u64 atomics (3 fields each)
constexpr int   kShards = 2;             // wave-parity shards (overflow headroom)
constexpr int   kCells  = 8192;          // interp cells over ts in [-1, 1]
constexpr int   kTM     = kCells + 1;    // table entries (8193)
constexpr float kInvDelta = 4096.0f;
constexpr float kDelta    = 1.0f / 4096.0f;
constexpr int   kShift    = 512;         // cells per bin shift of 1/8 (exact)
constexpr int   kThreads  = 1024;
constexpr int   kBlocksPerGroup = 32;
constexpr int   kK0Base   = 4096;        // k0 = (t+1)*4096 in [4096, 8192)
// Fixed-point packing (round-8 numerics, verified absmax 1.95e-3):
//  * 19-bit fields, 7-bit count at bit 57; scale 512, bias 2048.
//  * unbiased dither q = floor(f*512 + hash(i)) kills the deterministic
//    rounding bias that failed round 7 (1.245e-2 measured == predicted
//    781*0.41/256/100 linear accumulation).
constexpr float kScale    = 512.0f;
constexpr float kInvScale = 1.0f / 512.0f;
constexpr int   kBias     = 2048;
// d_ws: [0, 32772) scalar tab; [65536, +262144) packed Entry9 table
constexpr size_t kTab9Off = 65536;

// Fused prep-kernel block split: first kZeroBlocks zero d_out, rest build tab.
constexpr int kZeroBlocks  = 90;               // 90*256 = 23040 = out_size
constexpr int kTableBlocks = (kTM + 3) / 4;    // 4 waves/block build 4 points

__device__ __forceinline__ float lrelu(float z) { return z >= 0.f ? z : kNeg * z; }

// One 64B cache line per event: 9 fp32 values + 9 fp16 lerp-deltas.
struct alignas(16) Entry9 {
  float  v[9];     // 36 B
  __half d[9];     // 18 B
  __half pad[5];   // -> 64 B
};
static_assert(sizeof(Entry9) == 64, "Entry9 must be 64B");

union EntryLd { float4 q[4]; Entry9 e; };

} // namespace

// Fused: blocks [0, kZeroBlocks) zero d_out; blocks [kZeroBlocks, ...) build
// the MLP table (lrelu MLP is piecewise-linear in its scalar input ->
// tabulate + lerp). One wave per table point; lane owns hidden column `lane`
// (+64+lane for lanes<36); W2 row loads coalesced; shuffle-reduce.
__global__ __launch_bounds__(256) void prep_kernel(
    const float* __restrict__ W1, const float* __restrict__ b1,
    const float* __restrict__ W2, const float* __restrict__ b2,
    const float* __restrict__ W3, const float* __restrict__ b3,
    float* __restrict__ tab, float* __restrict__ out, int out_n) {
  if (blockIdx.x < kZeroBlocks) {
    int i = blockIdx.x * 256 + threadIdx.x;
    if (i < out_n) out[i] = 0.f;
    return;
  }
  int wave = ((blockIdx.x - kZeroBlocks) * 256 + threadIdx.x) >> 6;
  int lane = threadIdx.x & 63;
  if (wave >= kTM) return;
  float ts = -1.0f + (float)wave * kDelta;

  bool two = (lane < kHid - 64);
  float acc1 = 0.f, acc2 = 0.f;
  for (int j = 0; j < kHid; ++j) {
    float h1 = lrelu(fmaf(ts, W1[j], b1[j]));
    const float* row = W2 + j * kHid;
    acc1 = fmaf(h1, row[lane], acc1);
    float w2b = two ? row[64 + lane] : 0.f;
    acc2 = fmaf(h1, w2b, acc2);
  }
  float o = lrelu(acc1 + b2[lane]) * W3[lane];
  if (two) o += lrelu(acc2 + b2[64 + lane]) * W3[64 + lane];
#pragma unroll
  for (int off = 32; off >= 1; off >>= 1) o += __shfl_xor(o, off);
  if (lane == 0) tab[wave] = o + b3[0];
}

// Pack all 9 bins' (value, fp16 delta) per k0 into ONE 64B record (round 4:
// one line per event; gathers proven cheap).
__global__ void pack_table9_kernel(const float* __restrict__ tab,
                                   Entry9* __restrict__ tab9) {
  int i = blockIdx.x * blockDim.x + threadIdx.x;
  if (i >= 4096) return;
  EntryLd u;
#pragma unroll
  for (int b = 0; b < kC; ++b) {
    int k = i + kK0Base - kShift * b;       // in [0, 8191]
    float a = tab[k];
    u.e.v[b] = a;
    u.e.d[b] = __float2half(tab[k + 1] - a);
  }
#pragma unroll
  for (int b = 0; b < 5; ++b) u.e.pad[b] = __float2half(0.f);
  float4* dst = reinterpret_cast<float4*>(tab9 + i);
#pragma unroll
  for (int b = 0; b < 4; ++b) dst[b] = u.q[b];
}

// Measured model (rounds 1-8): LDS atomics cost ~3.3 cyc/lane/instruction,
// invariant to width (pk_f16 == f32 == u64), banks, occupancy, gather pipe
// -> instruction COUNT is the only knob (9->5 ops: 95->55.5us; 5->3 ops:
// 55.5->~27us, both matching the linear model). 3 ds_add_u64 per event is
// the bit-packing floor at required precision (2-word packings either
// overflow 14-bit fields or push dither noise past the 5.5e-3 threshold).
__global__ __launch_bounds__(kThreads) void scatter_kernel(
    const float4* __restrict__ events, const Entry9* __restrict__ tab9,
    float* __restrict__ out, int Ngroup) {
  __shared__ unsigned long long s_vox[kShards][kBase][kWords];  // 7680 B
  for (int i = threadIdx.x; i < kShards * kBase * kWords; i += kThreads)
    (&s_vox[0][0][0])[i] = 0ull;
  __syncthreads();

  int g   = blockIdx.x / kBlocksPerGroup;
  int sub = blockIdx.x % kBlocksPerGroup;
  int per = (Ngroup + kBlocksPerGroup - 1) / kBlocksPerGroup;
  int start = g * Ngroup + sub * per;
  int end   = g * Ngroup + min((sub + 1) * per, Ngroup);
  int shard = (threadIdx.x >> 6) & (kShards - 1);   // wave parity

  for (int i = start + (int)threadIdx.x; i < end; i += kThreads) {
    float4 e = events[i];              // (x, t, p, b)
    float t = e.y;
    int base = (int)e.z * kH + (int)e.x - 1;   // p*80 + (x-1), in [0,160)
    float u0 = fmaf(t, kInvDelta, kInvDelta);  // (t+1)*4096
    int   k0 = (int)u0;                        // in [4096, 8192)
    float fr = u0 - (float)k0;

    const float4* ep = reinterpret_cast<const float4*>(tab9 + (k0 - kK0Base));
    EntryLd u;
    u.q[0] = ep[0]; u.q[1] = ep[1]; u.q[2] = ep[2]; u.q[3] = ep[3];

    // per-event dither in [0,1): Knuth multiplicative hash of event index
    float dith = (float)((unsigned)i * 2654435761u >> 8) * (1.0f / 16777216.0f);

    int q[kC];
#pragma unroll
    for (int bin = 0; bin < kC; ++bin) {
      float f = t * fmaf(fr, __half2float(u.e.d[bin]), u.e.v[bin]);
      f = fminf(fmaxf(f, -3.9f), 3.9f);        // guards field overflow
      q[bin] = (int)floorf(fmaf(f, kScale, dith)) + kBias;  // in [0, 4045]
    }
    unsigned long long* sv = &s_vox[shard][base][0];
#pragma unroll
    for (int w = 0; w < kWords; ++w) {
      unsigned long long word =
          (1ull << 57) |
          ((unsigned long long)q[3 * w + 2] << 38) |
          ((unsigned long long)q[3 * w + 1] << 19) |
          (unsigned long long)q[3 * w + 0];
      atomicAdd(&sv[w], word);                 // ds_add_u64
    }
  }
  __syncthreads();

  float* og = out + g * kVoxLoc;
  for (int i = threadIdx.x; i < kVoxLoc; i += kThreads) {
    int bin  = i / kBase;              // out layout: [bin][base]
    int base = i - bin * kBase;
    int w = bin / 3, fld = bin - 3 * w;
    float v = 0.f;
#pragma unroll
    for (int s = 0; s < kShards; ++s) {
      unsigned long long word = s_vox[s][base][w];
      long long cnt = (long long)(word >> 57);
      long long raw = (long long)((word >> (19 * fld)) & 0x7FFFFull);
      v += (float)(raw - cnt * (long long)kBias) * kInvScale;
    }
    atomicAdd(&og[i], v * 0.01f);
  }
}

extern "C" void kernel_launch(void* const* d_in, const int* in_sizes, int n_in,
                              void* d_out, int out_size, void* d_ws, size_t ws_size,
                              hipStream_t stream) {
  const float4* events = (const float4*)d_in[0];
  const float* W1 = (const float*)d_in[1];
  const float* b1 = (const float*)d_in[2];
  const float* W2 = (const float*)d_in[3];
  const float* b2 = (const float*)d_in[4];
  const float* W3 = (const float*)d_in[5];
  const float* b3 = (const float*)d_in[6];
  float* out = (float*)d_out;
  float*  tab  = (float*)d_ws;
  Entry9* tab9 = (Entry9*)((char*)d_ws + kTab9Off);

  int N = in_sizes[0] / 4;
  int Ngroup = N / kB;

  prep_kernel<<<kZeroBlocks + kTableBlocks, 256, 0, stream>>>(
      W1, b1, W2, b2, W3, b3, tab, out, out_size);
  pack_table9_kernel<<<(4096 + 255) / 256, 256, 0, stream>>>(tab, tab9);
  scatter_kernel<<<kB * kBlocksPerGroup, kThreads, 0, stream>>>(
      events, tab9, out, Ngroup);
}